// Round 11
// baseline (90.090 us; speedup 1.0000x reference)
//
#include <hip/hip_runtime.h>

#define Bn 64
#define Tn 512
#define Ln 48
#define START_L 46
#define PAD_L 45
#define END_L 47
#define QP 72            // LDS pitch (ushorts) over kk=0..63 (+pad)
#define LSEG 8           // timesteps per segment
#define NBUF 16          // segments (= LDS buffers) per block; 2 per wave
#define NCHUNK (Tn / (LSEG * NBUF))   // 4 chunks per batch

typedef __bf16 bf16x8 __attribute__((ext_vector_type(8)));
typedef float f32x4 __attribute__((ext_vector_type(4)));
#define MFMA __builtin_amdgcn_mfma_f32_16x16x32_bf16

__device__ __forceinline__ unsigned short f2bf(float x) {
    unsigned u = __float_as_uint(x);
    u += 0x7fffu + ((u >> 16) & 1u);
    return (unsigned short)(u >> 16);
}
// truncation pack: low16 = bf16_trunc(a), high16 = bf16_trunc(b); 1 v_perm_b32
__device__ __forceinline__ unsigned pkT(float a, float b) {
    return __builtin_amdgcn_perm(__float_as_uint(b), __float_as_uint(a), 0x07060302u);
}
__device__ __forceinline__ float bcast0(float x) {
    return __int_as_float(__builtin_amdgcn_readfirstlane(__float_as_int(x)));
}
__device__ __forceinline__ float4 exp4(float4 v) {
    float4 r; r.x = __expf(v.x); r.y = __expf(v.y); r.z = __expf(v.z); r.w = __expf(v.w);
    return r;
}

// pi: kk = q4*16 + m16*4 + r  <->  row = m16*16 + q4*4 + r  (kk&15 >= 12 -> pad, zero)
// TB(X)[n*QP + kk] = X[pi(kk)][n].
// MFMA(TB(U) as A, TB(V) as B) = U^T * V (C layout out).  Verified r7-r9 (absmax 0).

__device__ __forceinline__ void readTB(const unsigned short* buf, int c, int q, bf16x8 F[3][2]) {
    #pragma unroll
    for (int x = 0; x < 3; ++x) {
        F[x][0] = *(const bf16x8*)&buf[(x * 16 + c) * QP + q * 8];
        F[x][1] = *(const bf16x8*)&buf[(x * 16 + c) * QP + 32 + q * 8];
    }
}

__device__ __forceinline__ void storeTB(unsigned short* buf, int c, int q,
                                        const f32x4 (&acc)[3][3],
                                        float4 w0, float4 w1, float4 w2) {
    #pragma unroll
    for (int nt = 0; nt < 3; ++nt) {
        unsigned u0 = pkT(acc[0][nt][0] * w0.x, acc[0][nt][1] * w0.y);
        unsigned u1 = pkT(acc[0][nt][2] * w0.z, acc[0][nt][3] * w0.w);
        unsigned u2 = pkT(acc[1][nt][0] * w1.x, acc[1][nt][1] * w1.y);
        unsigned u3 = pkT(acc[1][nt][2] * w1.z, acc[1][nt][3] * w1.w);
        unsigned u4 = pkT(acc[2][nt][0] * w2.x, acc[2][nt][1] * w2.y);
        unsigned u5 = pkT(acc[2][nt][2] * w2.z, acc[2][nt][3] * w2.w);
        unsigned short* wp = &buf[(nt * 16 + c) * QP + q * 16];
        uint4 s4; s4.x = u0; s4.y = u1; s4.z = u2; s4.w = u3;
        *(uint4*)wp = s4;
        uint2 s2; s2.x = u4; s2.y = u5;
        *(uint2*)(wp + 8) = s2;
    }
}

// one tree product: dst <- renorm(U^T * V); returns log(renorm)
__device__ __forceinline__ float treeProd(const unsigned short* bufA, const unsigned short* bufB,
                                          unsigned short* dst, int c, int q) {
    bf16x8 FA[3][2], FB[3][2];
    readTB(bufA, c, q, FA);
    readTB(bufB, c, q, FB);
    f32x4 acc[3][3];
    const f32x4 z = {0.f, 0.f, 0.f, 0.f};
    #pragma unroll
    for (int mt = 0; mt < 3; ++mt)
        #pragma unroll
        for (int nt = 0; nt < 3; ++nt) {
            acc[mt][nt] = MFMA(FA[mt][0], FB[nt][0], z, 0, 0, 0);
            acc[mt][nt] = MFMA(FA[mt][1], FB[nt][1], acc[mt][nt], 0, 0, 0);
        }
    float r = bcast0(acc[0][0][0]);
    float rr = __builtin_amdgcn_rcpf(r);
    float4 w; w.x = rr; w.y = rr; w.z = rr; w.w = rr;
    storeTB(dst, c, q, acc, w, w, w);
    return __logf(r);
}

// ---- fused dual-segment scan + 4-level in-block tree: 256 blocks x 8 waves --
__global__ __launch_bounds__(512, 2) void scan_k(
        const float* __restrict__ scores,
        const float* __restrict__ trans,
        unsigned short* __restrict__ ws2M,
        float* __restrict__ ws2S,
        float* __restrict__ out) {
    const int b   = blockIdx.x & (Bn - 1);
    const int cid = blockIdx.x >> 6;          // 0..NCHUNK-1
    const int tid = threadIdx.x;
    const int w   = tid >> 6;
    const int lane = tid & 63;
    const int c = lane & 15;
    const int q = lane >> 4;

    __shared__ __align__(16) unsigned short TBs[NBUF][48 * QP];
    __shared__ float scl[32];

    for (int i = tid; i < NBUF * 48 * QP / 4; i += 512)
        ((unsigned long long*)TBs)[i] = 0ull;
    __syncthreads();

    // wave w handles segments s1 = w, s2 = w+8 (block-local); both parity w&1
    const int dirOdd = w & 1;        // odd: transposed scan Y <- D_t E Y, t descending
    const int s1 = cid * NBUF + w;
    const int s2 = s1 + 8;
    const int t0a = s1 * LSEG, tea = t0a + LSEG - 1;
    const int t0b = s2 * LSEG, teb = t0b + LSEG - 1;
    const float* sb = scores + (size_t)b * Tn * Ln;

    // static A frags: even = E^T (pi on k), odd = E (pi on k); trunc-packed pairs
    bf16x8 A[3][2];
    #pragma unroll
    for (int mt = 0; mt < 3; ++mt)
        #pragma unroll
        for (int kt = 0; kt < 2; ++kt) {
            union { unsigned u[4]; bf16x8 v; } fu;
            #pragma unroll
            for (int j2 = 0; j2 < 4; ++j2) {
                int kk0 = kt * 32 + q * 8 + 2 * j2;
                int rem = kk0 & 15;
                if (rem < 12) {
                    int row0 = (rem >> 2) * 16 + (kk0 >> 4) * 4 + (kk0 & 3);
                    float tv0 = dirOdd ? trans[(mt * 16 + c) * Ln + row0]
                                       : trans[row0 * Ln + mt * 16 + c];
                    float tv1 = dirOdd ? trans[(mt * 16 + c) * Ln + row0 + 1]
                                       : trans[(row0 + 1) * Ln + mt * 16 + c];
                    fu.u[j2] = pkT(__expf(tv0), __expf(tv1));
                } else fu.u[j2] = 0u;
            }
            A[mt][kt] = fu.v;
        }

    unsigned short* TB0 = TBs[w];
    unsigned short* TB1 = TBs[w + 8];

    // init: even -> diag(esc_t0) in pi space; odd -> identity
    if (lane < Ln) {
        int m16 = lane >> 4, q4 = (lane >> 2) & 3, r = lane & 3;
        int kk = q4 * 16 + m16 * 4 + r;
        TB0[lane * QP + kk] = dirOdd ? (unsigned short)0x3F80
                                     : f2bf(__expf(sb[(size_t)t0a * Ln + lane]));
        TB1[lane * QP + kk] = dirOdd ? (unsigned short)0x3F80
                                     : f2bf(__expf(sb[(size_t)t0b * Ln + lane]));
    }

    // esc scale index at round tau: even -> t0+1+tau, odd -> tend-tau (clamped)
    auto clampA = [&](int t) { return t < t0a ? t0a : (t > tea ? tea : t); };
    auto clampB = [&](int t) { return t < t0b ? t0b : (t > teb ? teb : t); };

    float4 wA0, wA1, wA2, wB0, wB1, wB2;
    {
        const float* rp = sb + (size_t)(dirOdd ? tea : (t0a + 1)) * Ln;
        wA0 = exp4(*(const float4*)(rp + q * 4));
        wA1 = exp4(*(const float4*)(rp + 16 + q * 4));
        wA2 = exp4(*(const float4*)(rp + 32 + q * 4));
        const float* rp2 = sb + (size_t)(dirOdd ? teb : (t0b + 1)) * Ln;
        wB0 = exp4(*(const float4*)(rp2 + q * 4));
        wB1 = exp4(*(const float4*)(rp2 + 16 + q * 4));
        wB2 = exp4(*(const float4*)(rp2 + 32 + q * 4));
    }

    f32x4 acc0[3][3], acc1[3][3];
    float Cs0 = 0.f, Cs1 = 0.f;
    for (int tau = 0; tau < LSEG; ++tau) {
        bf16x8 Bf0[3][2], Bf1[3][2];
        readTB(TB0, c, q, Bf0);
        readTB(TB1, c, q, Bf1);

        // distance-1 prefetch of next esc rows (raw; exp applied after MFMAs)
        int tnA = clampA(dirOdd ? (tea - (tau + 1)) : (t0a + 2 + tau));
        int tnB = clampB(dirOdd ? (teb - (tau + 1)) : (t0b + 2 + tau));
        const float* rpA = sb + (size_t)tnA * Ln;
        const float* rpB = sb + (size_t)tnB * Ln;
        float4 nA0 = *(const float4*)(rpA + q * 4);
        float4 nA1 = *(const float4*)(rpA + 16 + q * 4);
        float4 nA2 = *(const float4*)(rpA + 32 + q * 4);
        float4 nB0 = *(const float4*)(rpB + q * 4);
        float4 nB1 = *(const float4*)(rpB + 16 + q * 4);
        float4 nB2 = *(const float4*)(rpB + 32 + q * 4);

        const f32x4 z = {0.f, 0.f, 0.f, 0.f};
        #pragma unroll
        for (int mt = 0; mt < 3; ++mt)
            #pragma unroll
            for (int nt = 0; nt < 3; ++nt) {
                acc0[mt][nt] = MFMA(A[mt][0], Bf0[nt][0], z, 0, 0, 0);
                acc0[mt][nt] = MFMA(A[mt][1], Bf0[nt][1], acc0[mt][nt], 0, 0, 0);
            }
        #pragma unroll
        for (int mt = 0; mt < 3; ++mt)
            #pragma unroll
            for (int nt = 0; nt < 3; ++nt) {
                acc1[mt][nt] = MFMA(A[mt][0], Bf1[nt][0], z, 0, 0, 0);
                acc1[mt][nt] = MFMA(A[mt][1], Bf1[nt][1], acc1[mt][nt], 0, 0, 0);
            }

        const bool lastEven = (!dirOdd && tau == LSEG - 1);
        const bool doRenorm = (tau & 3) == 0;

        // chain 0
        {
            float4 w0 = wA0, w1 = wA1, w2 = wA2;
            if (lastEven) { w0.x = w0.y = w0.z = w0.w = 1.f; w1 = w0; w2 = w0; }
            if (doRenorm) {
                float r = bcast0(acc0[0][0][0]);
                float rr = __builtin_amdgcn_rcpf(r);
                Cs0 += __logf(r);
                w0.x *= rr; w0.y *= rr; w0.z *= rr; w0.w *= rr;
                w1.x *= rr; w1.y *= rr; w1.z *= rr; w1.w *= rr;
                w2.x *= rr; w2.y *= rr; w2.z *= rr; w2.w *= rr;
            }
            storeTB(TB0, c, q, acc0, w0, w1, w2);
        }
        // chain 1
        {
            float4 w0 = wB0, w1 = wB1, w2 = wB2;
            if (lastEven) { w0.x = w0.y = w0.z = w0.w = 1.f; w1 = w0; w2 = w0; }
            if (doRenorm) {
                float r = bcast0(acc1[0][0][0]);
                float rr = __builtin_amdgcn_rcpf(r);
                Cs1 += __logf(r);
                w0.x *= rr; w0.y *= rr; w0.z *= rr; w0.w *= rr;
                w1.x *= rr; w1.y *= rr; w1.z *= rr; w1.w *= rr;
                w2.x *= rr; w2.y *= rr; w2.z *= rr; w2.w *= rr;
            }
            storeTB(TB1, c, q, acc1, w0, w1, w2);
        }

        wA0 = exp4(nA0); wA1 = exp4(nA1); wA2 = exp4(nA2);
        wB0 = exp4(nB0); wB1 = exp4(nB1); wB2 = exp4(nB2);
    }
    if (lane == 0) { scl[w] = Cs0; scl[w + 8] = Cs1; }
    __syncthreads();

    // tree L1: i=w (0..7): G_i = P_{2i+1} P_{2i}; even i normal, odd i transposed; dst buf 2i
    {
        int i = w;
        const unsigned short* bufA = TBs[2 * i + ((i & 1) ? 0 : 1)];
        const unsigned short* bufB = TBs[2 * i + ((i & 1) ? 1 : 0)];
        float lg = treeProd(bufA, bufB, TBs[2 * i], c, q);
        if (lane == 0) scl[16 + i] = lg;
    }
    __syncthreads();
    // L2: j=w<4: K_j from bufs 4j,4j+2; dst 4j
    if (w < 4) {
        int j = w;
        const unsigned short* bufA = TBs[4 * j + ((j & 1) ? 0 : 2)];
        const unsigned short* bufB = TBs[4 * j + ((j & 1) ? 2 : 0)];
        float lg = treeProd(bufA, bufB, TBs[4 * j], c, q);
        if (lane == 0) scl[24 + j] = lg;
    }
    __syncthreads();
    // L3: p=w<2: M_p from bufs 8p,8p+4; dst 8p
    if (w < 2) {
        int p = w;
        const unsigned short* bufA = TBs[8 * p + ((p & 1) ? 0 : 4)];
        const unsigned short* bufB = TBs[8 * p + ((p & 1) ? 4 : 0)];
        float lg = treeProd(bufA, bufB, TBs[8 * p], c, q);
        if (lane == 0) scl[28 + p] = lg;
    }
    __syncthreads();
    // L4: F = M_1 M_0 = H(M_1^T, M_0) -> global row-major + total log-scale
    if (w == 0) {
        bf16x8 FA[3][2], FB[3][2];
        readTB(TBs[8], c, q, FA);
        readTB(TBs[0], c, q, FB);
        f32x4 pac[3][3];
        const f32x4 z = {0.f, 0.f, 0.f, 0.f};
        #pragma unroll
        for (int mt = 0; mt < 3; ++mt)
            #pragma unroll
            for (int nt = 0; nt < 3; ++nt) {
                pac[mt][nt] = MFMA(FA[mt][0], FB[nt][0], z, 0, 0, 0);
                pac[mt][nt] = MFMA(FA[mt][1], FB[nt][1], pac[mt][nt], 0, 0, 0);
            }
        float r = bcast0(pac[0][0][0]);
        float rr = __builtin_amdgcn_rcpf(r);
        float Ct = __logf(r);
        #pragma unroll
        for (int i2 = 0; i2 < 30; ++i2) Ct += scl[i2];
        unsigned short* mp = ws2M + (size_t)blockIdx.x * (Ln * Ln);
        #pragma unroll
        for (int mt = 0; mt < 3; ++mt)
            #pragma unroll
            for (int nt = 0; nt < 3; ++nt)
                #pragma unroll
                for (int r2 = 0; r2 < 4; ++r2)
                    mp[(mt * 16 + q * 4 + r2) * Ln + nt * 16 + c] = f2bf(pac[mt][nt][r2] * rr);
        if (lane == 0) ws2S[blockIdx.x] = Ct;
    }
    if (blockIdx.x == 0 && tid == 0) out[0] = 0.f;
}

// ---------------- fold 4 chunk matrices into vector + gold (r9-verified) ----
__global__ __launch_bounds__(64) void fin_k(
        const float* __restrict__ scores,
        const int* __restrict__ gold,
        const int* __restrict__ mask,
        const float* __restrict__ trans,
        const unsigned short* __restrict__ ws2M,
        const float* __restrict__ ws2S,
        float* __restrict__ out) {
    const int b = blockIdx.x;
    const int lane = threadIdx.x;
    const int j = (lane < Ln) ? lane : (Ln - 1);

    __shared__ float vB[64];

    float v = (lane < Ln) ? __expf(trans[START_L * Ln + lane]) : 0.0f;
    float Ctot = 0.0f;

    uint4 rows[NCHUNK][6];
    #pragma unroll
    for (int s2 = 0; s2 < NCHUNK; ++s2) {
        const unsigned short* p = ws2M + (size_t)(s2 * Bn + b) * (Ln * Ln) + (size_t)j * Ln;
        #pragma unroll
        for (int k = 0; k < 6; ++k) rows[s2][k] = *(const uint4*)(p + k * 8);
    }

    #pragma unroll
    for (int s2 = 0; s2 < NCHUNK; ++s2) {
        float Cs = ws2S[s2 * Bn + b];
        if (lane < Ln) vB[lane] = v;

        float a0 = 0.f, a1 = 0.f, a2 = 0.f, a3 = 0.f;
        #pragma unroll
        for (int k2 = 0; k2 < 12; ++k2) {
            float4 vb = *(const float4*)&vB[k2 * 4];
            uint4 ch = rows[s2][k2 >> 1];
            unsigned d0 = (k2 & 1) ? ch.z : ch.x;
            unsigned d1 = (k2 & 1) ? ch.w : ch.y;
            float f0 = __uint_as_float(d0 << 16);
            float f1 = __uint_as_float(d0 & 0xffff0000u);
            float f2 = __uint_as_float(d1 << 16);
            float f3 = __uint_as_float(d1 & 0xffff0000u);
            a0 = fmaf(f0, vb.x, a0);
            a1 = fmaf(f1, vb.y, a1);
            a2 = fmaf(f2, vb.z, a2);
            a3 = fmaf(f3, vb.w, a3);
        }
        float accv = (a0 + a1) + (a2 + a3);

        float r = bcast0(accv);
        v = accv * __builtin_amdgcn_rcpf(r);
        Ctot += __logf(r) + Cs;
    }

    if (lane == END_L) {
        atomicAdd(out, (__logf(v) + Ctot) * (1.0f / Bn));
    }

    float tgv = 0.0f;
    #pragma unroll
    for (int k = 0; k < Tn / 64; ++k) {
        int t = lane + k * 64;
        int idx = b * Tn + t;
        if (mask[idx]) tgv += scores[(size_t)idx * Ln] + trans[gold[idx]];
    }
    #pragma unroll
    for (int off = 32; off > 0; off >>= 1) tgv += __shfl_down(tgv, off);
    if (lane == 0) {
        float vv = -tgv * (1.0f / Bn);
        if (b == 0) vv -= trans[START_L];        // t=0 gold term
        atomicAdd(out, vv);
    }
}

extern "C" void kernel_launch(void* const* d_in, const int* in_sizes, int n_in,
                              void* d_out, int out_size, void* d_ws, size_t ws_size,
                              hipStream_t stream) {
    const float* scores = (const float*)d_in[0];
    const int*   gold   = (const int*)d_in[1];
    const int*   mask   = (const int*)d_in[2];
    const float* trans  = (const float*)d_in[3];
    float* out = (float*)d_out;

    unsigned short* ws2M = (unsigned short*)d_ws;
    float* ws2S = (float*)((char*)d_ws + (size_t)Bn * NCHUNK * Ln * Ln * 2);

    scan_k<<<Bn * NCHUNK, 512, 0, stream>>>(scores, trans, ws2M, ws2S, out);
    fin_k<<<Bn, 64, 0, stream>>>(scores, gold, mask, trans, ws2M, ws2S, out);
}

// Round 12
// 87.538 us; speedup vs baseline: 1.0292x; 1.0292x over previous
//
#include <hip/hip_runtime.h>

#define Bn 64
#define Tn 512
#define Ln 48
#define START_L 46
#define PAD_L 45
#define END_L 47
#define QP 72            // LDS pitch (ushorts) over kk=0..63 (+pad)
#define LSEG 8           // timesteps per segment
#define NBUF 16          // segments (= LDS buffers) per block; 2 per wave
#define NCHUNK (Tn / (LSEG * NBUF))   // 4 chunks per batch

typedef __bf16 bf16x8 __attribute__((ext_vector_type(8)));
typedef float f32x4 __attribute__((ext_vector_type(4)));
#define MFMA __builtin_amdgcn_mfma_f32_16x16x32_bf16

__device__ __forceinline__ unsigned short f2bf(float x) {
    unsigned u = __float_as_uint(x);
    u += 0x7fffu + ((u >> 16) & 1u);
    return (unsigned short)(u >> 16);
}
// truncation pack: low16 = bf16_trunc(a), high16 = bf16_trunc(b); 1 v_perm_b32
__device__ __forceinline__ unsigned pkT(float a, float b) {
    return __builtin_amdgcn_perm(__float_as_uint(b), __float_as_uint(a), 0x07060302u);
}
__device__ __forceinline__ float bcast0(float x) {
    return __int_as_float(__builtin_amdgcn_readfirstlane(__float_as_int(x)));
}
__device__ __forceinline__ float4 exp4(float4 v) {
    float4 r; r.x = __expf(v.x); r.y = __expf(v.y); r.z = __expf(v.z); r.w = __expf(v.w);
    return r;
}

// pi: kk = q4*16 + m16*4 + r  <->  row = m16*16 + q4*4 + r  (kk&15 >= 12 -> pad, zero)
// TB(X)[n*QP + kk] = X[pi(kk)][n].
// MFMA(TB(U) as A, TB(V) as B) = U^T * V (C layout out).  Verified r7-r11 (absmax 0).

__device__ __forceinline__ void readTB(const unsigned short* buf, int c, int q, bf16x8 F[3][2]) {
    #pragma unroll
    for (int x = 0; x < 3; ++x) {
        F[x][0] = *(const bf16x8*)&buf[(x * 16 + c) * QP + q * 8];
        F[x][1] = *(const bf16x8*)&buf[(x * 16 + c) * QP + 32 + q * 8];
    }
}

__device__ __forceinline__ void storeTB(unsigned short* buf, int c, int q,
                                        const f32x4 (&acc)[3][3],
                                        float4 w0, float4 w1, float4 w2) {
    #pragma unroll
    for (int nt = 0; nt < 3; ++nt) {
        unsigned u0 = pkT(acc[0][nt][0] * w0.x, acc[0][nt][1] * w0.y);
        unsigned u1 = pkT(acc[0][nt][2] * w0.z, acc[0][nt][3] * w0.w);
        unsigned u2 = pkT(acc[1][nt][0] * w1.x, acc[1][nt][1] * w1.y);
        unsigned u3 = pkT(acc[1][nt][2] * w1.z, acc[1][nt][3] * w1.w);
        unsigned u4 = pkT(acc[2][nt][0] * w2.x, acc[2][nt][1] * w2.y);
        unsigned u5 = pkT(acc[2][nt][2] * w2.z, acc[2][nt][3] * w2.w);
        unsigned short* wp = &buf[(nt * 16 + c) * QP + q * 16];
        uint4 s4; s4.x = u0; s4.y = u1; s4.z = u2; s4.w = u3;
        *(uint4*)wp = s4;
        uint2 s2; s2.x = u4; s2.y = u5;
        *(uint2*)(wp + 8) = s2;
    }
}

// one tree product: dst <- renorm(U^T * V); returns log(renorm)
__device__ __forceinline__ float treeProd(const unsigned short* bufA, const unsigned short* bufB,
                                          unsigned short* dst, int c, int q) {
    bf16x8 FA[3][2], FB[3][2];
    readTB(bufA, c, q, FA);
    readTB(bufB, c, q, FB);
    f32x4 acc[3][3];
    const f32x4 z = {0.f, 0.f, 0.f, 0.f};
    #pragma unroll
    for (int mt = 0; mt < 3; ++mt)
        #pragma unroll
        for (int nt = 0; nt < 3; ++nt) {
            acc[mt][nt] = MFMA(FA[mt][0], FB[nt][0], z, 0, 0, 0);
            acc[mt][nt] = MFMA(FA[mt][1], FB[nt][1], acc[mt][nt], 0, 0, 0);
        }
    float r = bcast0(acc[0][0][0]);
    float rr = __builtin_amdgcn_rcpf(r);
    float4 w; w.x = rr; w.y = rr; w.z = rr; w.w = rr;
    storeTB(dst, c, q, acc, w, w, w);
    return __logf(r);
}

// ---- fused dual-segment scan + 4-level in-block tree: 256 blocks x 8 waves --
__global__ __launch_bounds__(512, 2) void scan_k(
        const float* __restrict__ scores,
        const float* __restrict__ trans,
        unsigned short* __restrict__ ws2M,
        float* __restrict__ ws2S,
        float* __restrict__ out) {
    const int b   = blockIdx.x & (Bn - 1);
    const int cid = blockIdx.x >> 6;          // 0..NCHUNK-1
    const int tid = threadIdx.x;
    const int w   = tid >> 6;
    const int lane = tid & 63;
    const int c = lane & 15;
    const int q = lane >> 4;

    __shared__ __align__(16) unsigned short TBs[NBUF][48 * QP];
    __shared__ float scl[32];

    for (int i = tid; i < NBUF * 48 * QP / 4; i += 512)
        ((unsigned long long*)TBs)[i] = 0ull;
    __syncthreads();

    // wave w handles segments s1 = w, s2 = w+8 (block-local); both parity w&1
    const int dirOdd = w & 1;        // odd: transposed scan Y <- D_t E Y, t descending
    const int s1 = cid * NBUF + w;
    const int s2 = s1 + 8;
    const int t0a = s1 * LSEG, tea = t0a + LSEG - 1;
    const int t0b = s2 * LSEG, teb = t0b + LSEG - 1;
    const float* sb = scores + (size_t)b * Tn * Ln;

    // static A frags: even = E^T (pi on k), odd = E (pi on k); trunc-packed pairs
    bf16x8 A[3][2];
    #pragma unroll
    for (int mt = 0; mt < 3; ++mt)
        #pragma unroll
        for (int kt = 0; kt < 2; ++kt) {
            union { unsigned u[4]; bf16x8 v; } fu;
            #pragma unroll
            for (int j2 = 0; j2 < 4; ++j2) {
                int kk0 = kt * 32 + q * 8 + 2 * j2;
                int rem = kk0 & 15;
                if (rem < 12) {
                    int row0 = (rem >> 2) * 16 + (kk0 >> 4) * 4 + (kk0 & 3);
                    float tv0 = dirOdd ? trans[(mt * 16 + c) * Ln + row0]
                                       : trans[row0 * Ln + mt * 16 + c];
                    float tv1 = dirOdd ? trans[(mt * 16 + c) * Ln + row0 + 1]
                                       : trans[(row0 + 1) * Ln + mt * 16 + c];
                    fu.u[j2] = pkT(__expf(tv0), __expf(tv1));
                } else fu.u[j2] = 0u;
            }
            A[mt][kt] = fu.v;
        }

    unsigned short* TB0 = TBs[w];
    unsigned short* TB1 = TBs[w + 8];

    // init: even -> diag(esc_t0) in pi space; odd -> identity
    if (lane < Ln) {
        int m16 = lane >> 4, q4 = (lane >> 2) & 3, r = lane & 3;
        int kk = q4 * 16 + m16 * 4 + r;
        TB0[lane * QP + kk] = dirOdd ? (unsigned short)0x3F80
                                     : f2bf(__expf(sb[(size_t)t0a * Ln + lane]));
        TB1[lane * QP + kk] = dirOdd ? (unsigned short)0x3F80
                                     : f2bf(__expf(sb[(size_t)t0b * Ln + lane]));
    }

    f32x4 acc0[3][3], acc1[3][3];
    float Cs0 = 0.f, Cs1 = 0.f;
    for (int tau = 0; tau < LSEG; ++tau) {
        // esc row indices for this round (even: t0+1+tau fwd; odd: tend-tau bwd)
        int tA = dirOdd ? (tea - tau) : (t0a + 1 + tau);
        if (tA > tea) tA = tea;
        int tB = dirOdd ? (teb - tau) : (t0b + 1 + tau);
        if (tB > teb) tB = teb;
        const float* rpA = sb + (size_t)tA * Ln;
        const float* rpB = sb + (size_t)tB * Ln;
        // issue raw loads early; exp applied after the MFMA wall
        float4 rA0 = *(const float4*)(rpA + q * 4);
        float4 rA1 = *(const float4*)(rpA + 16 + q * 4);
        float4 rA2 = *(const float4*)(rpA + 32 + q * 4);
        float4 rB0 = *(const float4*)(rpB + q * 4);
        float4 rB1 = *(const float4*)(rpB + 16 + q * 4);
        float4 rB2 = *(const float4*)(rpB + 32 + q * 4);

        bf16x8 Bf0[3][2], Bf1[3][2];
        readTB(TB0, c, q, Bf0);
        readTB(TB1, c, q, Bf1);

        const f32x4 z = {0.f, 0.f, 0.f, 0.f};
        #pragma unroll
        for (int mt = 0; mt < 3; ++mt)
            #pragma unroll
            for (int nt = 0; nt < 3; ++nt) {
                acc0[mt][nt] = MFMA(A[mt][0], Bf0[nt][0], z, 0, 0, 0);
                acc0[mt][nt] = MFMA(A[mt][1], Bf0[nt][1], acc0[mt][nt], 0, 0, 0);
            }
        #pragma unroll
        for (int mt = 0; mt < 3; ++mt)
            #pragma unroll
            for (int nt = 0; nt < 3; ++nt) {
                acc1[mt][nt] = MFMA(A[mt][0], Bf1[nt][0], z, 0, 0, 0);
                acc1[mt][nt] = MFMA(A[mt][1], Bf1[nt][1], acc1[mt][nt], 0, 0, 0);
            }

        const bool lastEven = (!dirOdd && tau == LSEG - 1);
        const bool doRenorm = (tau == 0);      // once per 8-step segment

        // chain 0
        {
            float4 w0, w1, w2;
            if (lastEven) {
                w0.x = w0.y = w0.z = w0.w = 1.f; w1 = w0; w2 = w0;
            } else {
                w0 = exp4(rA0); w1 = exp4(rA1); w2 = exp4(rA2);
            }
            if (doRenorm) {
                float r = bcast0(acc0[0][0][0]);
                float rr = __builtin_amdgcn_rcpf(r);
                Cs0 += __logf(r);
                w0.x *= rr; w0.y *= rr; w0.z *= rr; w0.w *= rr;
                w1.x *= rr; w1.y *= rr; w1.z *= rr; w1.w *= rr;
                w2.x *= rr; w2.y *= rr; w2.z *= rr; w2.w *= rr;
            }
            storeTB(TB0, c, q, acc0, w0, w1, w2);
        }
        // chain 1
        {
            float4 w0, w1, w2;
            if (lastEven) {
                w0.x = w0.y = w0.z = w0.w = 1.f; w1 = w0; w2 = w0;
            } else {
                w0 = exp4(rB0); w1 = exp4(rB1); w2 = exp4(rB2);
            }
            if (doRenorm) {
                float r = bcast0(acc1[0][0][0]);
                float rr = __builtin_amdgcn_rcpf(r);
                Cs1 += __logf(r);
                w0.x *= rr; w0.y *= rr; w0.z *= rr; w0.w *= rr;
                w1.x *= rr; w1.y *= rr; w1.z *= rr; w1.w *= rr;
                w2.x *= rr; w2.y *= rr; w2.z *= rr; w2.w *= rr;
            }
            storeTB(TB1, c, q, acc1, w0, w1, w2);
        }
    }
    if (lane == 0) { scl[w] = Cs0; scl[w + 8] = Cs1; }
    __syncthreads();

    // tree L1: i=w (0..7): G_i = P_{2i+1} P_{2i}; even i normal, odd i transposed; dst buf 2i
    {
        int i = w;
        const unsigned short* bufA = TBs[2 * i + ((i & 1) ? 0 : 1)];
        const unsigned short* bufB = TBs[2 * i + ((i & 1) ? 1 : 0)];
        float lg = treeProd(bufA, bufB, TBs[2 * i], c, q);
        if (lane == 0) scl[16 + i] = lg;
    }
    __syncthreads();
    // L2: j=w<4: K_j from bufs 4j,4j+2; dst 4j
    if (w < 4) {
        int j = w;
        const unsigned short* bufA = TBs[4 * j + ((j & 1) ? 0 : 2)];
        const unsigned short* bufB = TBs[4 * j + ((j & 1) ? 2 : 0)];
        float lg = treeProd(bufA, bufB, TBs[4 * j], c, q);
        if (lane == 0) scl[24 + j] = lg;
    }
    __syncthreads();
    // L3: p=w<2: M_p from bufs 8p,8p+4; dst 8p
    if (w < 2) {
        int p = w;
        const unsigned short* bufA = TBs[8 * p + ((p & 1) ? 0 : 4)];
        const unsigned short* bufB = TBs[8 * p + ((p & 1) ? 4 : 0)];
        float lg = treeProd(bufA, bufB, TBs[8 * p], c, q);
        if (lane == 0) scl[28 + p] = lg;
    }
    __syncthreads();
    // L4: F = M_1 M_0 = H(M_1^T, M_0) -> global row-major + total log-scale
    if (w == 0) {
        bf16x8 FA[3][2], FB[3][2];
        readTB(TBs[8], c, q, FA);
        readTB(TBs[0], c, q, FB);
        f32x4 pac[3][3];
        const f32x4 z = {0.f, 0.f, 0.f, 0.f};
        #pragma unroll
        for (int mt = 0; mt < 3; ++mt)
            #pragma unroll
            for (int nt = 0; nt < 3; ++nt) {
                pac[mt][nt] = MFMA(FA[mt][0], FB[nt][0], z, 0, 0, 0);
                pac[mt][nt] = MFMA(FA[mt][1], FB[nt][1], pac[mt][nt], 0, 0, 0);
            }
        float r = bcast0(pac[0][0][0]);
        float rr = __builtin_amdgcn_rcpf(r);
        float Ct = __logf(r);
        #pragma unroll
        for (int i2 = 0; i2 < 30; ++i2) Ct += scl[i2];
        unsigned short* mp = ws2M + (size_t)blockIdx.x * (Ln * Ln);
        #pragma unroll
        for (int mt = 0; mt < 3; ++mt)
            #pragma unroll
            for (int nt = 0; nt < 3; ++nt)
                #pragma unroll
                for (int r2 = 0; r2 < 4; ++r2)
                    mp[(mt * 16 + q * 4 + r2) * Ln + nt * 16 + c] = f2bf(pac[mt][nt][r2] * rr);
        if (lane == 0) ws2S[blockIdx.x] = Ct;
    }
    if (blockIdx.x == 0 && tid == 0) out[0] = 0.f;
}

// ------ fold 4 chunk matrices into vector (wave 0) + gold (4 waves) ---------
__global__ __launch_bounds__(256) void fin_k(
        const float* __restrict__ scores,
        const int* __restrict__ gold,
        const int* __restrict__ mask,
        const float* __restrict__ trans,
        const unsigned short* __restrict__ ws2M,
        const float* __restrict__ ws2S,
        float* __restrict__ out) {
    const int b = blockIdx.x;
    const int tid = threadIdx.x;
    const int wv = tid >> 6;
    const int lane = tid & 63;

    __shared__ float vB[64];
    __shared__ float gred[4];

    // ---- gold-path energy: 4 waves x 2 t's each
    float tgv = 0.0f;
    #pragma unroll
    for (int k = 0; k < 2; ++k) {
        int idx = b * Tn + tid + k * 256;
        if (mask[idx]) tgv += scores[(size_t)idx * Ln] + trans[gold[idx]];
    }
    #pragma unroll
    for (int off = 32; off > 0; off >>= 1) tgv += __shfl_down(tgv, off);
    if (lane == 0) gred[wv] = tgv;
    __syncthreads();
    if (tid == 0) {
        float s = gred[0] + gred[1] + gred[2] + gred[3];
        float vv = -s * (1.0f / Bn);
        if (b == 0) vv -= trans[START_L];        // t=0 gold term
        atomicAdd(out, vv);
    }

    // ---- vector fold on wave 0
    if (wv == 0) {
        const int j = (lane < Ln) ? lane : (Ln - 1);
        float v = (lane < Ln) ? __expf(trans[START_L * Ln + lane]) : 0.0f;
        float Ctot = 0.0f;

        uint4 rows[NCHUNK][6];
        #pragma unroll
        for (int s2 = 0; s2 < NCHUNK; ++s2) {
            const unsigned short* p = ws2M + (size_t)(s2 * Bn + b) * (Ln * Ln) + (size_t)j * Ln;
            #pragma unroll
            for (int k = 0; k < 6; ++k) rows[s2][k] = *(const uint4*)(p + k * 8);
        }

        #pragma unroll
        for (int s2 = 0; s2 < NCHUNK; ++s2) {
            float Cs = ws2S[s2 * Bn + b];
            if (lane < Ln) vB[lane] = v;

            float a0 = 0.f, a1 = 0.f, a2 = 0.f, a3 = 0.f;
            #pragma unroll
            for (int k2 = 0; k2 < 12; ++k2) {
                float4 vb = *(const float4*)&vB[k2 * 4];
                uint4 ch = rows[s2][k2 >> 1];
                unsigned d0 = (k2 & 1) ? ch.z : ch.x;
                unsigned d1 = (k2 & 1) ? ch.w : ch.y;
                float f0 = __uint_as_float(d0 << 16);
                float f1 = __uint_as_float(d0 & 0xffff0000u);
                float f2 = __uint_as_float(d1 << 16);
                float f3 = __uint_as_float(d1 & 0xffff0000u);
                a0 = fmaf(f0, vb.x, a0);
                a1 = fmaf(f1, vb.y, a1);
                a2 = fmaf(f2, vb.z, a2);
                a3 = fmaf(f3, vb.w, a3);
            }
            float accv = (a0 + a1) + (a2 + a3);

            float r = bcast0(accv);
            v = accv * __builtin_amdgcn_rcpf(r);
            Ctot += __logf(r) + Cs;
        }

        if (lane == END_L) {
            atomicAdd(out, (__logf(v) + Ctot) * (1.0f / Bn));
        }
    }
}

extern "C" void kernel_launch(void* const* d_in, const int* in_sizes, int n_in,
                              void* d_out, int out_size, void* d_ws, size_t ws_size,
                              hipStream_t stream) {
    const float* scores = (const float*)d_in[0];
    const int*   gold   = (const int*)d_in[1];
    const int*   mask   = (const int*)d_in[2];
    const float* trans  = (const float*)d_in[3];
    float* out = (float*)d_out;

    unsigned short* ws2M = (unsigned short*)d_ws;
    float* ws2S = (float*)((char*)d_ws + (size_t)Bn * NCHUNK * Ln * Ln * 2);

    scan_k<<<Bn * NCHUNK, 512, 0, stream>>>(scores, trans, ws2M, ws2S, out);
    fin_k<<<Bn, 256, 0, stream>>>(scores, gold, mask, trans, ws2M, ws2S, out);
}

// Round 13
// 83.572 us; speedup vs baseline: 1.0780x; 1.0475x over previous
//
#include <hip/hip_runtime.h>

#define Bn 64
#define Tn 512
#define Ln 48
#define START_L 46
#define PAD_L 45
#define END_L 47
#define QP 72            // LDS pitch (ushorts) over kk=0..63 (+pad)
#define LSEG 16          // timesteps per segment
#define NSEG 8           // segments (= waves) per block; block = 1 chunk
#define NCHUNK (Tn / (LSEG * NSEG))   // 4 chunks per batch

typedef __bf16 bf16x8 __attribute__((ext_vector_type(8)));
typedef float f32x4 __attribute__((ext_vector_type(4)));
#define MFMA __builtin_amdgcn_mfma_f32_16x16x32_bf16

__device__ __forceinline__ unsigned short f2bf(float x) {
    unsigned u = __float_as_uint(x);
    u += 0x7fffu + ((u >> 16) & 1u);
    return (unsigned short)(u >> 16);
}
// truncation pack: low16 = bf16_trunc(a), high16 = bf16_trunc(b); 1 v_perm_b32
__device__ __forceinline__ unsigned pkT(float a, float b) {
    return __builtin_amdgcn_perm(__float_as_uint(b), __float_as_uint(a), 0x07060302u);
}
__device__ __forceinline__ float bcast0(float x) {
    return __int_as_float(__builtin_amdgcn_readfirstlane(__float_as_int(x)));
}
__device__ __forceinline__ float4 exp4(float4 v) {
    float4 r; r.x = __expf(v.x); r.y = __expf(v.y); r.z = __expf(v.z); r.w = __expf(v.w);
    return r;
}

// pi: kk = q4*16 + m16*4 + r  <->  row = m16*16 + q4*4 + r  (kk&15 >= 12 -> pad, zero)
// TB(X)[n*QP + kk] = X[pi(kk)][n].
// MFMA(TB(U) as A, TB(V) as B) = U^T * V (C layout out).  Verified r7-r12 (absmax 0).

__device__ __forceinline__ void readTB(const unsigned short* buf, int c, int q, bf16x8 F[3][2]) {
    #pragma unroll
    for (int x = 0; x < 3; ++x) {
        F[x][0] = *(const bf16x8*)&buf[(x * 16 + c) * QP + q * 8];
        F[x][1] = *(const bf16x8*)&buf[(x * 16 + c) * QP + 32 + q * 8];
    }
}

__device__ __forceinline__ void storeTB(unsigned short* buf, int c, int q,
                                        const f32x4 (&acc)[3][3],
                                        float4 w0, float4 w1, float4 w2) {
    #pragma unroll
    for (int nt = 0; nt < 3; ++nt) {
        unsigned u0 = pkT(acc[0][nt][0] * w0.x, acc[0][nt][1] * w0.y);
        unsigned u1 = pkT(acc[0][nt][2] * w0.z, acc[0][nt][3] * w0.w);
        unsigned u2 = pkT(acc[1][nt][0] * w1.x, acc[1][nt][1] * w1.y);
        unsigned u3 = pkT(acc[1][nt][2] * w1.z, acc[1][nt][3] * w1.w);
        unsigned u4 = pkT(acc[2][nt][0] * w2.x, acc[2][nt][1] * w2.y);
        unsigned u5 = pkT(acc[2][nt][2] * w2.z, acc[2][nt][3] * w2.w);
        unsigned short* wp = &buf[(nt * 16 + c) * QP + q * 16];
        uint4 s4; s4.x = u0; s4.y = u1; s4.z = u2; s4.w = u3;
        *(uint4*)wp = s4;
        uint2 s2; s2.x = u4; s2.y = u5;
        *(uint2*)(wp + 8) = s2;
    }
}

// one tree product: dst <- renorm(U^T * V); returns log(renorm)
__device__ __forceinline__ float treeProd(const unsigned short* bufA, const unsigned short* bufB,
                                          unsigned short* dst, int c, int q) {
    bf16x8 FA[3][2], FB[3][2];
    readTB(bufA, c, q, FA);
    readTB(bufB, c, q, FB);
    f32x4 acc[3][3];
    const f32x4 z = {0.f, 0.f, 0.f, 0.f};
    #pragma unroll
    for (int mt = 0; mt < 3; ++mt)
        #pragma unroll
        for (int nt = 0; nt < 3; ++nt) {
            acc[mt][nt] = MFMA(FA[mt][0], FB[nt][0], z, 0, 0, 0);
            acc[mt][nt] = MFMA(FA[mt][1], FB[nt][1], acc[mt][nt], 0, 0, 0);
        }
    float r = bcast0(acc[0][0][0]);
    float rr = __builtin_amdgcn_rcpf(r);
    float4 w; w.x = rr; w.y = rr; w.z = rr; w.w = rr;
    storeTB(dst, c, q, acc, w, w, w);
    return __logf(r);
}

// ---------- fused scan + in-block tree fold: 256 blocks x 8 waves ----------
__global__ __launch_bounds__(512, 2) void scan_k(
        const float* __restrict__ scores,
        const float* __restrict__ trans,
        unsigned short* __restrict__ ws2M,
        float* __restrict__ ws2S,
        float* __restrict__ out) {
    const int b   = blockIdx.x & (Bn - 1);
    const int cid = blockIdx.x >> 6;          // 0..NCHUNK-1
    const int tid = threadIdx.x;
    const int w   = tid >> 6;
    const int lane = tid & 63;
    const int c = lane & 15;
    const int q = lane >> 4;

    __shared__ __align__(16) unsigned short TBs[NSEG][48 * QP];
    __shared__ float scl[16];

    for (int i = tid; i < NSEG * 48 * QP / 4; i += 512)
        ((unsigned long long*)TBs)[i] = 0ull;
    __syncthreads();

    const int s    = cid * NSEG + w;
    const int t0   = s * LSEG;
    const int tend = t0 + LSEG - 1;
    const int dirOdd = w & 1;        // odd wave: transposed scan Y <- D_t E Y, t descending
    const float* sb = scores + (size_t)b * Tn * Ln;

    // static A frags: even = E^T (pi on k), odd = E (pi on k); trunc-packed pairs
    bf16x8 A[3][2];
    #pragma unroll
    for (int mt = 0; mt < 3; ++mt)
        #pragma unroll
        for (int kt = 0; kt < 2; ++kt) {
            union { unsigned u[4]; bf16x8 v; } fu;
            #pragma unroll
            for (int j2 = 0; j2 < 4; ++j2) {
                int kk0 = kt * 32 + q * 8 + 2 * j2;
                int rem = kk0 & 15;
                if (rem < 12) {
                    int row0 = (rem >> 2) * 16 + (kk0 >> 4) * 4 + (kk0 & 3);
                    float tv0 = dirOdd ? trans[(mt * 16 + c) * Ln + row0]
                                       : trans[row0 * Ln + mt * 16 + c];
                    float tv1 = dirOdd ? trans[(mt * 16 + c) * Ln + row0 + 1]
                                       : trans[(row0 + 1) * Ln + mt * 16 + c];
                    fu.u[j2] = pkT(__expf(tv0), __expf(tv1));
                } else fu.u[j2] = 0u;
            }
            A[mt][kt] = fu.v;
        }

    unsigned short* myTB = TBs[w];

    // init: even -> diag(esc_t0) in pi space; odd -> identity
    if (lane < Ln) {
        int m16 = lane >> 4, q4 = (lane >> 2) & 3, r = lane & 3;
        int kk = q4 * 16 + m16 * 4 + r;
        myTB[lane * QP + kk] = dirOdd ? (unsigned short)0x3F80
                                      : f2bf(__expf(sb[(size_t)t0 * Ln + lane]));
    }

    // esc pipeline: round tau scales by esc(t0+1+tau) [even] / esc(tend-tau) [odd]
    float4 wA, wB, wC, rA, rB, rC;
    {
        int t1 = dirOdd ? tend : (t0 + 1);
        const float* rp = sb + (size_t)t1 * Ln;
        wA = exp4(*(const float4*)(rp + q * 4));
        wB = exp4(*(const float4*)(rp + 16 + q * 4));
        wC = exp4(*(const float4*)(rp + 32 + q * 4));
        int t2 = dirOdd ? (tend - 1) : (t0 + 2);
        const float* rp2 = sb + (size_t)t2 * Ln;
        rA = *(const float4*)(rp2 + q * 4);
        rB = *(const float4*)(rp2 + 16 + q * 4);
        rC = *(const float4*)(rp2 + 32 + q * 4);
    }

    f32x4 acc[3][3];
    float Cs = 0.f;
    for (int tau = 0; tau < LSEG; ++tau) {
        bf16x8 Bf[3][2];
        readTB(myTB, c, q, Bf);

        int tp = dirOdd ? (tend - (tau + 2)) : (t0 + 3 + tau);
        if (tp < t0) tp = t0;
        if (tp > tend) tp = tend;
        const float* rp3 = sb + (size_t)tp * Ln;
        float4 nA = *(const float4*)(rp3 + q * 4);
        float4 nB = *(const float4*)(rp3 + 16 + q * 4);
        float4 nC = *(const float4*)(rp3 + 32 + q * 4);

        const f32x4 z = {0.f, 0.f, 0.f, 0.f};
        #pragma unroll
        for (int mt = 0; mt < 3; ++mt)
            #pragma unroll
            for (int nt = 0; nt < 3; ++nt) {
                acc[mt][nt] = MFMA(A[mt][0], Bf[nt][0], z, 0, 0, 0);
                acc[mt][nt] = MFMA(A[mt][1], Bf[nt][1], acc[mt][nt], 0, 0, 0);
            }

        float4 w0 = wA, w1 = wB, w2 = wC;
        if (!dirOdd && tau == LSEG - 1) {      // even scan: no trailing D
            w0.x = w0.y = w0.z = w0.w = 1.f; w1 = w0; w2 = w0;
        }
        if ((tau & 3) == 0) {                  // renorm every 4 rounds
            float r = bcast0(acc[0][0][0]);
            float rr = __builtin_amdgcn_rcpf(r);
            Cs += __logf(r);
            w0.x *= rr; w0.y *= rr; w0.z *= rr; w0.w *= rr;
            w1.x *= rr; w1.y *= rr; w1.z *= rr; w1.w *= rr;
            w2.x *= rr; w2.y *= rr; w2.z *= rr; w2.w *= rr;
        }
        storeTB(myTB, c, q, acc, w0, w1, w2);

        wA = rA; wB = rB; wC = rC;
        rA = nA; rB = nB; rC = nC;
        wA = exp4(wA); wB = exp4(wB); wC = exp4(wC);
    }
    if (lane == 0) scl[w] = Cs;
    __syncthreads();

    // tree level 1: G_i = S_{2i+1} S_{2i} (even i) / G_i^T (odd i) -> buf 2i
    if (w < 4) {
        const unsigned short* bufA = TBs[(w & 1) ? (2 * w) : (2 * w + 1)];
        const unsigned short* bufB = TBs[(w & 1) ? (2 * w + 1) : (2 * w)];
        float lg = treeProd(bufA, bufB, TBs[2 * w], c, q);
        if (lane == 0) scl[8 + w] = lg;
    }
    __syncthreads();
    // level 2: K0 = H(G1^T, G0) -> buf0 ; K1^T = H(G2, G3^T) -> buf4
    if (w < 2) {
        const unsigned short* bufA = TBs[w ? 4 : 2];
        const unsigned short* bufB = TBs[w ? 6 : 0];
        float lg = treeProd(bufA, bufB, TBs[w ? 4 : 0], c, q);
        if (lane == 0) scl[12 + w] = lg;
    }
    __syncthreads();
    // level 3: C = H(K1^T, K0) -> global (row-major) + total log-scale
    if (w == 0) {
        bf16x8 FA[3][2], FB[3][2];
        readTB(TBs[4], c, q, FA);
        readTB(TBs[0], c, q, FB);
        f32x4 pac[3][3];
        const f32x4 z = {0.f, 0.f, 0.f, 0.f};
        #pragma unroll
        for (int mt = 0; mt < 3; ++mt)
            #pragma unroll
            for (int nt = 0; nt < 3; ++nt) {
                pac[mt][nt] = MFMA(FA[mt][0], FB[nt][0], z, 0, 0, 0);
                pac[mt][nt] = MFMA(FA[mt][1], FB[nt][1], pac[mt][nt], 0, 0, 0);
            }
        float r = bcast0(pac[0][0][0]);
        float rr = __builtin_amdgcn_rcpf(r);
        float Ct = __logf(r);
        #pragma unroll
        for (int i2 = 0; i2 < 14; ++i2) Ct += scl[i2];
        unsigned short* mp = ws2M + (size_t)blockIdx.x * (Ln * Ln);
        #pragma unroll
        for (int mt = 0; mt < 3; ++mt)
            #pragma unroll
            for (int nt = 0; nt < 3; ++nt)
                #pragma unroll
                for (int r2 = 0; r2 < 4; ++r2)
                    mp[(mt * 16 + q * 4 + r2) * Ln + nt * 16 + c] = f2bf(pac[mt][nt][r2] * rr);
        if (lane == 0) ws2S[blockIdx.x] = Ct;
    }
    if (blockIdx.x == 0 && tid == 0) out[0] = 0.f;
}

// ------ fold 4 chunk matrices into vector (wave 0) + gold (4 waves) ---------
__global__ __launch_bounds__(256) void fin_k(
        const float* __restrict__ scores,
        const int* __restrict__ gold,
        const int* __restrict__ mask,
        const float* __restrict__ trans,
        const unsigned short* __restrict__ ws2M,
        const float* __restrict__ ws2S,
        float* __restrict__ out) {
    const int b = blockIdx.x;
    const int tid = threadIdx.x;
    const int wv = tid >> 6;
    const int lane = tid & 63;

    __shared__ float vB[64];
    __shared__ float gred[4];

    // ---- gold-path energy: 4 waves x 2 t's each
    float tgv = 0.0f;
    #pragma unroll
    for (int k = 0; k < 2; ++k) {
        int idx = b * Tn + tid + k * 256;
        if (mask[idx]) tgv += scores[(size_t)idx * Ln] + trans[gold[idx]];
    }
    #pragma unroll
    for (int off = 32; off > 0; off >>= 1) tgv += __shfl_down(tgv, off);
    if (lane == 0) gred[wv] = tgv;
    __syncthreads();
    if (tid == 0) {
        float s = gred[0] + gred[1] + gred[2] + gred[3];
        float vv = -s * (1.0f / Bn);
        if (b == 0) vv -= trans[START_L];        // t=0 gold term
        atomicAdd(out, vv);
    }

    // ---- vector fold on wave 0
    if (wv == 0) {
        const int j = (lane < Ln) ? lane : (Ln - 1);
        float v = (lane < Ln) ? __expf(trans[START_L * Ln + lane]) : 0.0f;
        float Ctot = 0.0f;

        uint4 rows[NCHUNK][6];
        #pragma unroll
        for (int s2 = 0; s2 < NCHUNK; ++s2) {
            const unsigned short* p = ws2M + (size_t)(s2 * Bn + b) * (Ln * Ln) + (size_t)j * Ln;
            #pragma unroll
            for (int k = 0; k < 6; ++k) rows[s2][k] = *(const uint4*)(p + k * 8);
        }

        #pragma unroll
        for (int s2 = 0; s2 < NCHUNK; ++s2) {
            float Cs = ws2S[s2 * Bn + b];
            if (lane < Ln) vB[lane] = v;

            float a0 = 0.f, a1 = 0.f, a2 = 0.f, a3 = 0.f;
            #pragma unroll
            for (int k2 = 0; k2 < 12; ++k2) {
                float4 vb = *(const float4*)&vB[k2 * 4];
                uint4 ch = rows[s2][k2 >> 1];
                unsigned d0 = (k2 & 1) ? ch.z : ch.x;
                unsigned d1 = (k2 & 1) ? ch.w : ch.y;
                float f0 = __uint_as_float(d0 << 16);
                float f1 = __uint_as_float(d0 & 0xffff0000u);
                float f2 = __uint_as_float(d1 << 16);
                float f3 = __uint_as_float(d1 & 0xffff0000u);
                a0 = fmaf(f0, vb.x, a0);
                a1 = fmaf(f1, vb.y, a1);
                a2 = fmaf(f2, vb.z, a2);
                a3 = fmaf(f3, vb.w, a3);
            }
            float accv = (a0 + a1) + (a2 + a3);

            float r = bcast0(accv);
            v = accv * __builtin_amdgcn_rcpf(r);
            Ctot += __logf(r) + Cs;
        }

        if (lane == END_L) {
            atomicAdd(out, (__logf(v) + Ctot) * (1.0f / Bn));
        }
    }
}

extern "C" void kernel_launch(void* const* d_in, const int* in_sizes, int n_in,
                              void* d_out, int out_size, void* d_ws, size_t ws_size,
                              hipStream_t stream) {
    const float* scores = (const float*)d_in[0];
    const int*   gold   = (const int*)d_in[1];
    const int*   mask   = (const int*)d_in[2];
    const float* trans  = (const float*)d_in[3];
    float* out = (float*)d_out;

    unsigned short* ws2M = (unsigned short*)d_ws;
    float* ws2S = (float*)((char*)d_ws + (size_t)Bn * NCHUNK * Ln * Ln * 2);

    scan_k<<<Bn * NCHUNK, 512, 0, stream>>>(scores, trans, ws2M, ws2S, out);
    fin_k<<<Bn, 256, 0, stream>>>(scores, gold, mask, trans, ws2M, ws2S, out);
}

// Round 14
// 83.296 us; speedup vs baseline: 1.0816x; 1.0033x over previous
//
#include <hip/hip_runtime.h>

#define Bn 64
#define Tn 512
#define Ln 48
#define START_L 46
#define PAD_L 45
#define END_L 47
#define QP 72            // LDS pitch (ushorts) over kk=0..63 (+pad)
#define LSEG 16          // timesteps per segment
#define NSEG 8           // segments (= waves) per block; block = 1 chunk
#define NCHUNK (Tn / (LSEG * NSEG))   // 4 chunks per batch

typedef __bf16 bf16x8 __attribute__((ext_vector_type(8)));
typedef float f32x4 __attribute__((ext_vector_type(4)));
#define MFMA __builtin_amdgcn_mfma_f32_16x16x32_bf16

__device__ __forceinline__ unsigned short f2bf(float x) {
    unsigned u = __float_as_uint(x);
    u += 0x7fffu + ((u >> 16) & 1u);
    return (unsigned short)(u >> 16);
}
// truncation pack: low16 = bf16_trunc(a), high16 = bf16_trunc(b); 1 v_perm_b32
__device__ __forceinline__ unsigned pkT(float a, float b) {
    return __builtin_amdgcn_perm(__float_as_uint(b), __float_as_uint(a), 0x07060302u);
}
__device__ __forceinline__ float bcast0(float x) {
    return __int_as_float(__builtin_amdgcn_readfirstlane(__float_as_int(x)));
}
__device__ __forceinline__ float4 exp4(float4 v) {
    float4 r; r.x = __expf(v.x); r.y = __expf(v.y); r.z = __expf(v.z); r.w = __expf(v.w);
    return r;
}
// Schraudolph fast exp: 2 full-rate VALU ops (fma + cvt) vs mul + 1/4-rate v_exp.
// rel err ~2-3% -> accumulated log bias ~5-15 absolute on ~1.17e5 output
// (bf16 output ulp = 512, threshold 2345). x = -10000 -> cvt saturates -> -0.0 == exp(-1e4).
__device__ __forceinline__ float sexp(float x) {
    return __int_as_float((int)fmaf(x, 12102203.0f, 1064866805.0f));
}
__device__ __forceinline__ float4 fexp4(float4 v) {
    float4 r; r.x = sexp(v.x); r.y = sexp(v.y); r.z = sexp(v.z); r.w = sexp(v.w);
    return r;
}

// pi: kk = q4*16 + m16*4 + r  <->  row = m16*16 + q4*4 + r  (kk&15 >= 12 -> pad, zero)
// TB(X)[n*QP + kk] = X[pi(kk)][n].
// MFMA(TB(U) as A, TB(V) as B) = U^T * V (C layout out).  Verified r7-r13 (absmax 0).

__device__ __forceinline__ void readTB(const unsigned short* buf, int c, int q, bf16x8 F[3][2]) {
    #pragma unroll
    for (int x = 0; x < 3; ++x) {
        F[x][0] = *(const bf16x8*)&buf[(x * 16 + c) * QP + q * 8];
        F[x][1] = *(const bf16x8*)&buf[(x * 16 + c) * QP + 32 + q * 8];
    }
}

__device__ __forceinline__ void storeTB(unsigned short* buf, int c, int q,
                                        const f32x4 (&acc)[3][3],
                                        float4 w0, float4 w1, float4 w2) {
    #pragma unroll
    for (int nt = 0; nt < 3; ++nt) {
        unsigned u0 = pkT(acc[0][nt][0] * w0.x, acc[0][nt][1] * w0.y);
        unsigned u1 = pkT(acc[0][nt][2] * w0.z, acc[0][nt][3] * w0.w);
        unsigned u2 = pkT(acc[1][nt][0] * w1.x, acc[1][nt][1] * w1.y);
        unsigned u3 = pkT(acc[1][nt][2] * w1.z, acc[1][nt][3] * w1.w);
        unsigned u4 = pkT(acc[2][nt][0] * w2.x, acc[2][nt][1] * w2.y);
        unsigned u5 = pkT(acc[2][nt][2] * w2.z, acc[2][nt][3] * w2.w);
        unsigned short* wp = &buf[(nt * 16 + c) * QP + q * 16];
        uint4 s4; s4.x = u0; s4.y = u1; s4.z = u2; s4.w = u3;
        *(uint4*)wp = s4;
        uint2 s2; s2.x = u4; s2.y = u5;
        *(uint2*)(wp + 8) = s2;
    }
}

// one tree product: dst <- renorm(U^T * V); returns log(renorm)
__device__ __forceinline__ float treeProd(const unsigned short* bufA, const unsigned short* bufB,
                                          unsigned short* dst, int c, int q) {
    bf16x8 FA[3][2], FB[3][2];
    readTB(bufA, c, q, FA);
    readTB(bufB, c, q, FB);
    f32x4 acc[3][3];
    const f32x4 z = {0.f, 0.f, 0.f, 0.f};
    #pragma unroll
    for (int mt = 0; mt < 3; ++mt)
        #pragma unroll
        for (int nt = 0; nt < 3; ++nt) {
            acc[mt][nt] = MFMA(FA[mt][0], FB[nt][0], z, 0, 0, 0);
            acc[mt][nt] = MFMA(FA[mt][1], FB[nt][1], acc[mt][nt], 0, 0, 0);
        }
    float r = bcast0(acc[0][0][0]);
    float rr = __builtin_amdgcn_rcpf(r);
    float4 w; w.x = rr; w.y = rr; w.z = rr; w.w = rr;
    storeTB(dst, c, q, acc, w, w, w);
    return __logf(r);
}

// ---------- fused scan + in-block tree fold: 256 blocks x 8 waves ----------
__global__ __launch_bounds__(512, 2) void scan_k(
        const float* __restrict__ scores,
        const float* __restrict__ trans,
        unsigned short* __restrict__ ws2M,
        float* __restrict__ ws2S,
        float* __restrict__ out) {
    const int b   = blockIdx.x & (Bn - 1);
    const int cid = blockIdx.x >> 6;          // 0..NCHUNK-1
    const int tid = threadIdx.x;
    const int w   = tid >> 6;
    const int lane = tid & 63;
    const int c = lane & 15;
    const int q = lane >> 4;

    __shared__ __align__(16) unsigned short TBs[NSEG][48 * QP];
    __shared__ float scl[16];

    for (int i = tid; i < NSEG * 48 * QP / 4; i += 512)
        ((unsigned long long*)TBs)[i] = 0ull;
    __syncthreads();

    const int s    = cid * NSEG + w;
    const int t0   = s * LSEG;
    const int tend = t0 + LSEG - 1;
    const int dirOdd = w & 1;        // odd wave: transposed scan Y <- D_t E Y, t descending
    const float* sb = scores + (size_t)b * Tn * Ln;

    // static A frags: even = E^T (pi on k), odd = E (pi on k); trunc-packed pairs
    bf16x8 A[3][2];
    #pragma unroll
    for (int mt = 0; mt < 3; ++mt)
        #pragma unroll
        for (int kt = 0; kt < 2; ++kt) {
            union { unsigned u[4]; bf16x8 v; } fu;
            #pragma unroll
            for (int j2 = 0; j2 < 4; ++j2) {
                int kk0 = kt * 32 + q * 8 + 2 * j2;
                int rem = kk0 & 15;
                if (rem < 12) {
                    int row0 = (rem >> 2) * 16 + (kk0 >> 4) * 4 + (kk0 & 3);
                    float tv0 = dirOdd ? trans[(mt * 16 + c) * Ln + row0]
                                       : trans[row0 * Ln + mt * 16 + c];
                    float tv1 = dirOdd ? trans[(mt * 16 + c) * Ln + row0 + 1]
                                       : trans[(row0 + 1) * Ln + mt * 16 + c];
                    fu.u[j2] = pkT(__expf(tv0), __expf(tv1));
                } else fu.u[j2] = 0u;
            }
            A[mt][kt] = fu.v;
        }

    unsigned short* myTB = TBs[w];

    // init: even -> diag(esc_t0) in pi space; odd -> identity
    if (lane < Ln) {
        int m16 = lane >> 4, q4 = (lane >> 2) & 3, r = lane & 3;
        int kk = q4 * 16 + m16 * 4 + r;
        myTB[lane * QP + kk] = dirOdd ? (unsigned short)0x3F80
                                      : f2bf(__expf(sb[(size_t)t0 * Ln + lane]));
    }

    // esc pipeline: round tau scales by esc(t0+1+tau) [even] / esc(tend-tau) [odd]
    float4 wA, wB, wC, rA, rB, rC;
    {
        int t1 = dirOdd ? tend : (t0 + 1);
        const float* rp = sb + (size_t)t1 * Ln;
        wA = fexp4(*(const float4*)(rp + q * 4));
        wB = fexp4(*(const float4*)(rp + 16 + q * 4));
        wC = fexp4(*(const float4*)(rp + 32 + q * 4));
        int t2 = dirOdd ? (tend - 1) : (t0 + 2);
        const float* rp2 = sb + (size_t)t2 * Ln;
        rA = *(const float4*)(rp2 + q * 4);
        rB = *(const float4*)(rp2 + 16 + q * 4);
        rC = *(const float4*)(rp2 + 32 + q * 4);
    }

    f32x4 acc[3][3];
    float Cs = 0.f;
    for (int tau = 0; tau < LSEG; ++tau) {
        bf16x8 Bf[3][2];
        readTB(myTB, c, q, Bf);

        int tp = dirOdd ? (tend - (tau + 2)) : (t0 + 3 + tau);
        if (tp < t0) tp = t0;
        if (tp > tend) tp = tend;
        const float* rp3 = sb + (size_t)tp * Ln;
        float4 nA = *(const float4*)(rp3 + q * 4);
        float4 nB = *(const float4*)(rp3 + 16 + q * 4);
        float4 nC = *(const float4*)(rp3 + 32 + q * 4);

        const f32x4 z = {0.f, 0.f, 0.f, 0.f};
        #pragma unroll
        for (int mt = 0; mt < 3; ++mt)
            #pragma unroll
            for (int nt = 0; nt < 3; ++nt) {
                acc[mt][nt] = MFMA(A[mt][0], Bf[nt][0], z, 0, 0, 0);
                acc[mt][nt] = MFMA(A[mt][1], Bf[nt][1], acc[mt][nt], 0, 0, 0);
            }

        float4 w0 = wA, w1 = wB, w2 = wC;
        if (!dirOdd && tau == LSEG - 1) {      // even scan: no trailing D
            w0.x = w0.y = w0.z = w0.w = 1.f; w1 = w0; w2 = w0;
        }
        if ((tau & 3) == 0) {                  // renorm every 4 rounds
            float r = bcast0(acc[0][0][0]);
            float rr = __builtin_amdgcn_rcpf(r);
            Cs += __logf(r);
            w0.x *= rr; w0.y *= rr; w0.z *= rr; w0.w *= rr;
            w1.x *= rr; w1.y *= rr; w1.z *= rr; w1.w *= rr;
            w2.x *= rr; w2.y *= rr; w2.z *= rr; w2.w *= rr;
        }
        storeTB(myTB, c, q, acc, w0, w1, w2);

        wA = fexp4(rA); wB = fexp4(rB); wC = fexp4(rC);
        rA = nA; rB = nB; rC = nC;
    }
    if (lane == 0) scl[w] = Cs;
    __syncthreads();

    // tree level 1: G_i = S_{2i+1} S_{2i} (even i) / G_i^T (odd i) -> buf 2i
    if (w < 4) {
        const unsigned short* bufA = TBs[(w & 1) ? (2 * w) : (2 * w + 1)];
        const unsigned short* bufB = TBs[(w & 1) ? (2 * w + 1) : (2 * w)];
        float lg = treeProd(bufA, bufB, TBs[2 * w], c, q);
        if (lane == 0) scl[8 + w] = lg;
    }
    __syncthreads();
    // level 2: K0 = H(G1^T, G0) -> buf0 ; K1^T = H(G2, G3^T) -> buf4
    if (w < 2) {
        const unsigned short* bufA = TBs[w ? 4 : 2];
        const unsigned short* bufB = TBs[w ? 6 : 0];
        float lg = treeProd(bufA, bufB, TBs[w ? 4 : 0], c, q);
        if (lane == 0) scl[12 + w] = lg;
    }
    __syncthreads();
    // level 3: C = H(K1^T, K0) -> global (row-major) + total log-scale
    if (w == 0) {
        bf16x8 FA[3][2], FB[3][2];
        readTB(TBs[4], c, q, FA);
        readTB(TBs[0], c, q, FB);
        f32x4 pac[3][3];
        const f32x4 z = {0.f, 0.f, 0.f, 0.f};
        #pragma unroll
        for (int mt = 0; mt < 3; ++mt)
            #pragma unroll
            for (int nt = 0; nt < 3; ++nt) {
                pac[mt][nt] = MFMA(FA[mt][0], FB[nt][0], z, 0, 0, 0);
                pac[mt][nt] = MFMA(FA[mt][1], FB[nt][1], pac[mt][nt], 0, 0, 0);
            }
        float r = bcast0(pac[0][0][0]);
        float rr = __builtin_amdgcn_rcpf(r);
        float Ct = __logf(r);
        #pragma unroll
        for (int i2 = 0; i2 < 14; ++i2) Ct += scl[i2];
        unsigned short* mp = ws2M + (size_t)blockIdx.x * (Ln * Ln);
        #pragma unroll
        for (int mt = 0; mt < 3; ++mt)
            #pragma unroll
            for (int nt = 0; nt < 3; ++nt)
                #pragma unroll
                for (int r2 = 0; r2 < 4; ++r2)
                    mp[(mt * 16 + q * 4 + r2) * Ln + nt * 16 + c] = f2bf(pac[mt][nt][r2] * rr);
        if (lane == 0) ws2S[blockIdx.x] = Ct;
    }
    if (blockIdx.x == 0 && tid == 0) out[0] = 0.f;
}

// ------ fold 4 chunk matrices into vector (wave 0) + gold (4 waves) ---------
__global__ __launch_bounds__(256) void fin_k(
        const float* __restrict__ scores,
        const int* __restrict__ gold,
        const int* __restrict__ mask,
        const float* __restrict__ trans,
        const unsigned short* __restrict__ ws2M,
        const float* __restrict__ ws2S,
        float* __restrict__ out) {
    const int b = blockIdx.x;
    const int tid = threadIdx.x;
    const int wv = tid >> 6;
    const int lane = tid & 63;

    __shared__ float vB[64];
    __shared__ float gred[4];

    // ---- gold-path energy: 4 waves x 2 t's each
    float tgv = 0.0f;
    #pragma unroll
    for (int k = 0; k < 2; ++k) {
        int idx = b * Tn + tid + k * 256;
        if (mask[idx]) tgv += scores[(size_t)idx * Ln] + trans[gold[idx]];
    }
    #pragma unroll
    for (int off = 32; off > 0; off >>= 1) tgv += __shfl_down(tgv, off);
    if (lane == 0) gred[wv] = tgv;
    __syncthreads();
    if (tid == 0) {
        float s = gred[0] + gred[1] + gred[2] + gred[3];
        float vv = -s * (1.0f / Bn);
        if (b == 0) vv -= trans[START_L];        // t=0 gold term
        atomicAdd(out, vv);
    }

    // ---- vector fold on wave 0
    if (wv == 0) {
        const int j = (lane < Ln) ? lane : (Ln - 1);
        float v = (lane < Ln) ? __expf(trans[START_L * Ln + lane]) : 0.0f;
        float Ctot = 0.0f;

        uint4 rows[NCHUNK][6];
        #pragma unroll
        for (int s2 = 0; s2 < NCHUNK; ++s2) {
            const unsigned short* p = ws2M + (size_t)(s2 * Bn + b) * (Ln * Ln) + (size_t)j * Ln;
            #pragma unroll
            for (int k = 0; k < 6; ++k) rows[s2][k] = *(const uint4*)(p + k * 8);
        }

        #pragma unroll
        for (int s2 = 0; s2 < NCHUNK; ++s2) {
            float Cs = ws2S[s2 * Bn + b];
            if (lane < Ln) vB[lane] = v;

            float a0 = 0.f, a1 = 0.f, a2 = 0.f, a3 = 0.f;
            #pragma unroll
            for (int k2 = 0; k2 < 12; ++k2) {
                float4 vb = *(const float4*)&vB[k2 * 4];
                uint4 ch = rows[s2][k2 >> 1];
                unsigned d0 = (k2 & 1) ? ch.z : ch.x;
                unsigned d1 = (k2 & 1) ? ch.w : ch.y;
                float f0 = __uint_as_float(d0 << 16);
                float f1 = __uint_as_float(d0 & 0xffff0000u);
                float f2 = __uint_as_float(d1 << 16);
                float f3 = __uint_as_float(d1 & 0xffff0000u);
                a0 = fmaf(f0, vb.x, a0);
                a1 = fmaf(f1, vb.y, a1);
                a2 = fmaf(f2, vb.z, a2);
                a3 = fmaf(f3, vb.w, a3);
            }
            float accv = (a0 + a1) + (a2 + a3);

            float r = bcast0(accv);
            v = accv * __builtin_amdgcn_rcpf(r);
            Ctot += __logf(r) + Cs;
        }

        if (lane == END_L) {
            atomicAdd(out, (__logf(v) + Ctot) * (1.0f / Bn));
        }
    }
}

extern "C" void kernel_launch(void* const* d_in, const int* in_sizes, int n_in,
                              void* d_out, int out_size, void* d_ws, size_t ws_size,
                              hipStream_t stream) {
    const float* scores = (const float*)d_in[0];
    const int*   gold   = (const int*)d_in[1];
    const int*   mask   = (const int*)d_in[2];
    const float* trans  = (const float*)d_in[3];
    float* out = (float*)d_out;

    unsigned short* ws2M = (unsigned short*)d_ws;
    float* ws2S = (float*)((char*)d_ws + (size_t)Bn * NCHUNK * Ln * Ln * 2);

    scan_k<<<Bn * NCHUNK, 512, 0, stream>>>(scores, trans, ws2M, ws2S, out);
    fin_k<<<Bn, 256, 0, stream>>>(scores, gold, mask, trans, ws2M, ws2S, out);
}